// Round 4
// baseline (67.509 us; speedup 1.0000x reference)
//
#include <hip/hip_runtime.h>
#include <math.h>

constexpr int T_LEN  = 8192;   // per-row length (== TREF)
constexpr int B_ROWS = 4096;
constexpr int NB     = 49;     // NBINS - 1 bins
constexpr int NC     = 32;     // histogram replicas (copy = tid & 31)
constexpr int HDIM   = 32;
constexpr float EPSF = 1e-10f;

// ---------------- kernel 1: rank-sort the reference into ws ----------------
// rank[i] = #{ j : ref[j] < ref[i]  ||  (ref[j] == ref[i] && j < i) }
// is an exact permutation -> sorted_out[rank[i]] = ref[i] is a full sort.
// 512 blocks; block handles 16 elements; 16 j-partitions of 512 per element.
__global__ __launch_bounds__(256)
void rank_sort_kernel(const float* __restrict__ ref, float* __restrict__ sorted_out) {
    __shared__ float vals[T_LEN];       // 32 KB
    __shared__ int   partial[256];
    const int tid = threadIdx.x;
    const float4* r4 = (const float4*)ref;
    float4* v4 = (float4*)vals;
    for (int i = tid; i < T_LEN / 4; i += 256) v4[i] = r4[i];
    __syncthreads();

    const int jpart = tid >> 4;         // wave-major: 16 lanes share one jpart -> broadcast reads
    const int iloc  = tid & 15;
    const int i     = blockIdx.x * 16 + iloc;
    const float x   = vals[i];
    int rank = 0;
    const int fbase = jpart * 128;      // float4 units, 128 per partition
    const int rot   = jpart * 34;      // stagger the 4 groups/wave across banks
    for (int t = 0; t < 128; ++t) {
        const int f = fbase + ((t + rot) & 127);
        const float4 y = v4[f];
        const int j = f * 4;
        rank += (y.x < x || (y.x == x && (j + 0) < i)) ? 1 : 0;
        rank += (y.y < x || (y.y == x && (j + 1) < i)) ? 1 : 0;
        rank += (y.z < x || (y.z == x && (j + 2) < i)) ? 1 : 0;
        rank += (y.w < x || (y.w == x && (j + 3) < i)) ? 1 : 0;
    }
    partial[tid] = rank;
    __syncthreads();
    if (tid < 16) {
        int r = 0;
        #pragma unroll
        for (int jp = 0; jp < 16; ++jp) r += partial[jp * 16 + tid];
        sorted_out[r] = vals[blockIdx.x * 16 + tid];
    }
}

// ---------------- kernel 2: fused per-row KL + MLP ----------------
// One block (256 threads) per row. Row in registers; current-row histogram via
// 32-replica LDS atomics; reference bin counts via 48 binary searches on the
// sorted reference (exact same counts as re-binning ref). Wave 0 does KL + MLP.
__global__ __launch_bounds__(256)
void kl_fused_kernel(const float* __restrict__ cur,
                     const float* __restrict__ sref,
                     const float* __restrict__ w1,
                     const float* __restrict__ b1,
                     const float* __restrict__ w2,
                     const float* __restrict__ b2,
                     float* __restrict__ kl_out,
                     float* __restrict__ enc_out) {
    __shared__ unsigned hq[NC * NB];
    __shared__ float rmn[4], rmx[4];

    const int b    = blockIdx.x;
    const int tid  = threadIdx.x;
    const int lane = tid & 63;
    const int wave = tid >> 6;

    for (int i = tid; i < NC * NB; i += 256) hq[i] = 0u;

    // ---- load row into registers, per-thread min/max ----
    const float4* src = (const float4*)(cur + (size_t)b * T_LEN);
    float4 v[8];
    float mn = 3.0e38f, mx = -3.0e38f;
    #pragma unroll
    for (int i = 0; i < 8; ++i) {
        v[i] = src[tid + i * 256];
        mn = fminf(mn, fminf(fminf(v[i].x, v[i].y), fminf(v[i].z, v[i].w)));
        mx = fmaxf(mx, fmaxf(fmaxf(v[i].x, v[i].y), fmaxf(v[i].z, v[i].w)));
    }
    #pragma unroll
    for (int off = 32; off > 0; off >>= 1) {
        mn = fminf(mn, __shfl_xor(mn, off));
        mx = fmaxf(mx, __shfl_xor(mx, off));
    }
    if (lane == 0) { rmn[wave] = mn; rmx[wave] = mx; }
    __syncthreads();   // also covers histogram zero-init

    const float cmin = fminf(fminf(rmn[0], rmn[1]), fminf(rmn[2], rmn[3]));
    const float cmax = fmaxf(fmaxf(rmx[0], rmx[1]), fmaxf(rmx[2], rmx[3]));
    const float lo = fminf(sref[0], cmin);
    const float hi = fmaxf(sref[T_LEN - 1], cmax);
    const float width = (hi - lo) / (float)NB;

    // ---- histogram current row (registers -> replicated LDS atomics) ----
    const float winv = 1.0f / width;
    const float nlw  = -lo * winv;
    unsigned* myq = hq + (tid & (NC - 1)) * NB;
    #pragma unroll
    for (int i = 0; i < 8; ++i) {
        int i0 = min(max((int)floorf(fmaf(v[i].x, winv, nlw)), 0), NB - 1);
        int i1 = min(max((int)floorf(fmaf(v[i].y, winv, nlw)), 0), NB - 1);
        int i2 = min(max((int)floorf(fmaf(v[i].z, winv, nlw)), 0), NB - 1);
        int i3 = min(max((int)floorf(fmaf(v[i].w, winv, nlw)), 0), NB - 1);
        atomicAdd(&myq[i0], 1u);
        atomicAdd(&myq[i1], 1u);
        atomicAdd(&myq[i2], 1u);
        atomicAdd(&myq[i3], 1u);
    }
    __syncthreads();

    // ---- KL over 49 bins + fused MLP on wave 0 ----
    if (tid < 64) {
        const bool act = tid < NB;
        // reference counts: C(k) = #{x : floor((x-lo)/width) <= k} via binary
        // search on sorted ref with the EXACT reference predicate.
        int C = T_LEN;
        if (tid < NB - 1) {                 // lanes 0..47
            const float kp1 = (float)(tid + 1);
            int l = 0, r = T_LEN;
            while (l < r) {
                const int m = (l + r) >> 1;
                const float xv = sref[m];
                if ((xv - lo) / width < kp1) l = m + 1; else r = m;
            }
            C = l;
        }
        int Cprev = __shfl_up(C, 1);
        if (tid == 0) Cprev = 0;

        float p = 0.0f, q = 0.0f;
        if (act) {
            unsigned sq = 0u;
            #pragma unroll
            for (int c = 0; c < NC; ++c) sq += hq[c * NB + tid];
            const float inv = 1.0f / ((float)T_LEN * width);
            p = (float)(C - Cprev) * inv + EPSF;
            q = (float)sq * inv + EPSF;
        }
        float P = p, Q = q;
        #pragma unroll
        for (int off = 32; off > 0; off >>= 1) {
            P += __shfl_xor(P, off);
            Q += __shfl_xor(Q, off);
        }
        float term = 0.0f;
        if (act) {
            const float pn = p / P;
            const float qn = q / Q;
            term = pn * logf(pn / qn);
        }
        #pragma unroll
        for (int off = 32; off > 0; off >>= 1) term += __shfl_xor(term, off);
        // after the butterfly every lane of wave 0 holds the full KL value
        if (tid == 0) kl_out[b] = term;

        if (tid < HDIM) {
            const float k = term;
            float acc = b2[tid];
            #pragma unroll
            for (int t = 0; t < HDIM; ++t) {
                float h = fmaxf(fmaf(k, w1[t], b1[t]), 0.0f);
                acc = fmaf(h, w2[tid * HDIM + t], acc);
            }
            enc_out[(size_t)b * HDIM + tid] = acc;
        }
    }
}

extern "C" void kernel_launch(void* const* d_in, const int* in_sizes, int n_in,
                              void* d_out, int out_size, void* d_ws, size_t ws_size,
                              hipStream_t stream) {
    const float* cur = (const float*)d_in[0];
    const float* ref = (const float*)d_in[1];
    const float* w1  = (const float*)d_in[2];
    const float* b1  = (const float*)d_in[3];
    const float* w2  = (const float*)d_in[4];
    const float* b2  = (const float*)d_in[5];
    float* out  = (float*)d_out;          // [0, B) = kl ; [B, B + B*H) = encoded
    float* sref = (float*)d_ws;           // 8192 sorted reference values

    rank_sort_kernel<<<T_LEN / 16, 256, 0, stream>>>(ref, sref);
    kl_fused_kernel<<<B_ROWS, 256, 0, stream>>>(
        cur, sref, w1, b1, w2, b2, out, out + B_ROWS);
}

// Round 5
// 43.151 us; speedup vs baseline: 1.5645x; 1.5645x over previous
//
#include <hip/hip_runtime.h>
#include <math.h>

constexpr int T_LEN  = 8192;   // per-row length (== TREF)
constexpr int B_ROWS = 4096;
constexpr int NB     = 49;     // NBINS - 1 bins
constexpr int NC     = 32;     // histogram replicas (copy = tid & 31)
constexpr int HDIM   = 32;
constexpr int FBINS  = 8192;   // fine CDF resolution
constexpr float EPSF = 1e-10f;

// ws layout (float units): [0]=rmin [1]=rmax ; int cdf[FBINS+1] at +8 ;
// float binned[T_LEN] (counting-sorted ref) at +8208
constexpr int WS_CDF_OFF    = 8;
constexpr int WS_BINNED_OFF = 8208;

// -------- kernel 1 (1 block): ref min/max + fine histogram + CDF + scatter ----
__global__ __launch_bounds__(256)
void ref_cdf_kernel(const float* __restrict__ ref, float* __restrict__ wsf) {
    __shared__ float sv[FBINS];      // 32 KB ref copy
    __shared__ int   hist[FBINS];    // 32 KB fine histogram -> exclusive scan
    __shared__ int   tsum[256];
    __shared__ float rmn4[4], rmx4[4];
    const int tid  = threadIdx.x;
    const int lane = tid & 63;
    const int wave = tid >> 6;

    const float4* r4 = (const float4*)ref;
    float4* sv4 = (float4*)sv;
    float mn = 3.0e38f, mx = -3.0e38f;
    #pragma unroll
    for (int i = 0; i < 8; ++i) {            // 8*256*4 = 8192 elements
        float4 v = r4[tid + i * 256];
        sv4[tid + i * 256] = v;
        mn = fminf(mn, fminf(fminf(v.x, v.y), fminf(v.z, v.w)));
        mx = fmaxf(mx, fmaxf(fmaxf(v.x, v.y), fmaxf(v.z, v.w)));
    }
    for (int i = tid; i < FBINS; i += 256) hist[i] = 0;
    #pragma unroll
    for (int off = 32; off > 0; off >>= 1) {
        mn = fminf(mn, __shfl_xor(mn, off));
        mx = fmaxf(mx, __shfl_xor(mx, off));
    }
    if (lane == 0) { rmn4[wave] = mn; rmx4[wave] = mx; }
    __syncthreads();
    const float rmin = fminf(fminf(rmn4[0], rmn4[1]), fminf(rmn4[2], rmn4[3]));
    const float rmax = fmaxf(fmaxf(rmx4[0], rmx4[1]), fmaxf(rmx4[2], rmx4[3]));
    const float finv = (float)FBINS / (rmax - rmin);

    // fine histogram (monotone binning rule)
    for (int i = tid; i < FBINS; i += 256) {
        int fb = min(max((int)floorf((sv[i] - rmin) * finv), 0), FBINS - 1);
        atomicAdd(&hist[fb], 1);
    }
    __syncthreads();

    // exclusive scan of hist (in place): local 32-seq + Hillis-Steele on totals
    const int base = tid * 32;
    int s = 0;
    #pragma unroll
    for (int i = 0; i < 32; ++i) { int h = hist[base + i]; hist[base + i] = s; s += h; }
    tsum[tid] = s;
    __syncthreads();
    for (int off = 1; off < 256; off <<= 1) {
        int v = (tid >= off) ? tsum[tid - off] : 0;
        __syncthreads();
        tsum[tid] += v;
        __syncthreads();
    }
    const int toff = (tid == 0) ? 0 : tsum[tid - 1];
    #pragma unroll
    for (int i = 0; i < 32; ++i) hist[base + i] += toff;
    __syncthreads();

    // publish pristine CDF, then scatter (hist doubles as running counters)
    int* cdf = (int*)(wsf + WS_CDF_OFF);
    for (int i = tid; i < FBINS; i += 256) cdf[i] = hist[i];
    if (tid == 0) { cdf[FBINS] = T_LEN; wsf[0] = rmin; wsf[1] = rmax; }
    __syncthreads();

    float* binned = wsf + WS_BINNED_OFF;
    for (int i = tid; i < FBINS; i += 256) {
        float x = sv[i];
        int fb = min(max((int)floorf((x - rmin) * finv), 0), FBINS - 1);
        int pos = atomicAdd(&hist[fb], 1);
        binned[pos] = x;
    }
}

// ---------------- kernel 2: fused per-row KL + MLP ----------------
// One block (256 threads) per row. Row in registers; current-row histogram via
// 32-replica LDS atomics; reference bin counts via exact CDF-window lookups.
__global__ __launch_bounds__(256)
void kl_fused_kernel(const float* __restrict__ cur,
                     const float* __restrict__ wsf,
                     const float* __restrict__ w1,
                     const float* __restrict__ b1,
                     const float* __restrict__ w2,
                     const float* __restrict__ b2,
                     float* __restrict__ kl_out,
                     float* __restrict__ enc_out) {
    __shared__ unsigned hq[NC * NB];
    __shared__ float rmn[4], rmx[4];

    const int b    = blockIdx.x;
    const int tid  = threadIdx.x;
    const int lane = tid & 63;
    const int wave = tid >> 6;

    for (int i = tid; i < NC * NB; i += 256) hq[i] = 0u;

    // ---- load row into registers, per-thread min/max ----
    const float4* src = (const float4*)(cur + (size_t)b * T_LEN);
    float4 v[8];
    float mn = 3.0e38f, mx = -3.0e38f;
    #pragma unroll
    for (int i = 0; i < 8; ++i) {
        v[i] = src[tid + i * 256];
        mn = fminf(mn, fminf(fminf(v[i].x, v[i].y), fminf(v[i].z, v[i].w)));
        mx = fmaxf(mx, fmaxf(fmaxf(v[i].x, v[i].y), fmaxf(v[i].z, v[i].w)));
    }
    #pragma unroll
    for (int off = 32; off > 0; off >>= 1) {
        mn = fminf(mn, __shfl_xor(mn, off));
        mx = fmaxf(mx, __shfl_xor(mx, off));
    }
    if (lane == 0) { rmn[wave] = mn; rmx[wave] = mx; }
    __syncthreads();   // also covers histogram zero-init

    const float rmin = wsf[0];
    const float rmax = wsf[1];
    const float cmin = fminf(fminf(rmn[0], rmn[1]), fminf(rmn[2], rmn[3]));
    const float cmax = fmaxf(fmaxf(rmx[0], rmx[1]), fmaxf(rmx[2], rmx[3]));
    const float lo = fminf(rmin, cmin);
    const float hi = fmaxf(rmax, cmax);
    const float width = (hi - lo) / (float)NB;

    // ---- histogram current row (registers -> replicated LDS atomics) ----
    const float winv = 1.0f / width;
    const float nlw  = -lo * winv;
    unsigned* myq = hq + (tid & (NC - 1)) * NB;
    #pragma unroll
    for (int i = 0; i < 8; ++i) {
        int i0 = min(max((int)floorf(fmaf(v[i].x, winv, nlw)), 0), NB - 1);
        int i1 = min(max((int)floorf(fmaf(v[i].y, winv, nlw)), 0), NB - 1);
        int i2 = min(max((int)floorf(fmaf(v[i].z, winv, nlw)), 0), NB - 1);
        int i3 = min(max((int)floorf(fmaf(v[i].w, winv, nlw)), 0), NB - 1);
        atomicAdd(&myq[i0], 1u);
        atomicAdd(&myq[i1], 1u);
        atomicAdd(&myq[i2], 1u);
        atomicAdd(&myq[i3], 1u);
    }
    __syncthreads();

    // ---- KL over 49 bins + fused MLP on wave 0 ----
    if (tid < 64) {
        const bool act = tid < NB;
        // reference cumulative counts C(k) = #{x : (x-lo)/width < k+1} via
        // fine-CDF window + exact predicate on the ambiguous fine bins.
        int C = T_LEN;
        if (tid < NB - 1) {                 // lanes 0..47
            const float kp1  = (float)(tid + 1);
            const float finv = (float)FBINS / (rmax - rmin);
            const int* cdf = (const int*)(wsf + WS_CDF_OFF);
            const float* binned = wsf + WS_BINNED_OFF;
            const float t = fmaf(width, kp1, lo);        // approx cut location
            int fb = (int)floorf((t - rmin) * finv);
            int a  = min(max(fb - 2, 0), FBINS);
            int bb = min(max(fb + 3, 0), FBINS);
            int ia = cdf[a], ib = cdf[bb];
            C = ia;
            for (int i = ia; i < ib; i += 4) {           // independent loads
                float x0 = binned[i];
                float x1 = (i + 1 < ib) ? binned[i + 1] : 3.0e38f;
                float x2 = (i + 2 < ib) ? binned[i + 2] : 3.0e38f;
                float x3 = (i + 3 < ib) ? binned[i + 3] : 3.0e38f;
                C += ((x0 - lo) / width < kp1) ? 1 : 0;
                C += ((x1 - lo) / width < kp1) ? 1 : 0;
                C += ((x2 - lo) / width < kp1) ? 1 : 0;
                C += ((x3 - lo) / width < kp1) ? 1 : 0;
            }
        }
        int Cprev = __shfl_up(C, 1);
        if (tid == 0) Cprev = 0;

        float p = 0.0f, q = 0.0f;
        if (act) {
            unsigned sq = 0u;
            #pragma unroll
            for (int c = 0; c < NC; ++c) sq += hq[c * NB + tid];
            const float inv = 1.0f / ((float)T_LEN * width);
            p = (float)(C - Cprev) * inv + EPSF;
            q = (float)sq * inv + EPSF;
        }
        float P = p, Q = q;
        #pragma unroll
        for (int off = 32; off > 0; off >>= 1) {
            P += __shfl_xor(P, off);
            Q += __shfl_xor(Q, off);
        }
        float term = 0.0f;
        if (act) {
            const float pn = p / P;
            const float qn = q / Q;
            term = pn * logf(pn / qn);
        }
        #pragma unroll
        for (int off = 32; off > 0; off >>= 1) term += __shfl_xor(term, off);
        // after the butterfly every lane of wave 0 holds the full KL value
        if (tid == 0) kl_out[b] = term;

        if (tid < HDIM) {
            const float k = term;
            float acc = b2[tid];
            #pragma unroll
            for (int t = 0; t < HDIM; ++t) {
                float h = fmaxf(fmaf(k, w1[t], b1[t]), 0.0f);
                acc = fmaf(h, w2[tid * HDIM + t], acc);
            }
            enc_out[(size_t)b * HDIM + tid] = acc;
        }
    }
}

extern "C" void kernel_launch(void* const* d_in, const int* in_sizes, int n_in,
                              void* d_out, int out_size, void* d_ws, size_t ws_size,
                              hipStream_t stream) {
    const float* cur = (const float*)d_in[0];
    const float* ref = (const float*)d_in[1];
    const float* w1  = (const float*)d_in[2];
    const float* b1  = (const float*)d_in[3];
    const float* w2  = (const float*)d_in[4];
    const float* b2  = (const float*)d_in[5];
    float* out = (float*)d_out;           // [0, B) = kl ; [B, B + B*H) = encoded
    float* wsf = (float*)d_ws;

    ref_cdf_kernel<<<1, 256, 0, stream>>>(ref, wsf);
    kl_fused_kernel<<<B_ROWS, 256, 0, stream>>>(
        cur, wsf, w1, b1, w2, b2, out, out + B_ROWS);
}